// Round 7
// baseline (272.892 us; speedup 1.0000x reference)
//
#include <hip/hip_runtime.h>

#define NQ 1764
#define NQP 1792             // keys padded to 28*64, zero-filled by prep
#define DIM 256
#define KT 32                // keys per attn tile
#define NT 56                // key tiles
#define QBLK 64              // queries per block (28 blocks/batch)

// ---- attn LDS map (halfword units) ----
// RM dbuf: 2 x 8192 @ 0          (QK operand, staged for tile t at iter t-1)
// TR dbuf: 2 x 8192 @ 16384      (PV operand, staged for tile t at iter t)
// P:       2 pairs x 2 bufs x 1280 @ 32768  (tile-parity double buffer)
// Lf:      64 floats @ 37888     (l handoff QK-waves -> PV-waves)
#define RM_SZ 8192
#define TR_SZ 8192
#define TR_OFF 16384
#define P_OFF 32768
#define P_STRIDE 40
#define L_OFF_HW 37888
#define SM_TOTAL 38016       // 76032 B -> 2 blocks/CU (8 waves/CU)

// ---- workspace map (ushort units) ----
#define WS_MRM_SZ (16 * NQP * DIM)
#define WS_MTR_SZ (16 * DIM * NQP)

typedef __attribute__((ext_vector_type(4))) short short4v;
typedef __attribute__((ext_vector_type(8))) short short8v;
typedef __attribute__((ext_vector_type(4))) float float4v;

static __device__ __forceinline__ ushort f2bf(float f) {
  union { float f; unsigned u; } v; v.f = f;
  return (ushort)((v.u + 0x7FFFu + ((v.u >> 16) & 1u)) >> 16);  // RNE
}

// async global->LDS DMA, 16 B per lane; LDS dest = wave-uniform base + lane*16
static __device__ __forceinline__ void dma16(const void* g, void* l) {
  __builtin_amdgcn_global_load_lds(
      (__attribute__((address_space(1))) void*)(void*)g,
      (__attribute__((address_space(3))) void*)l, 16, 0, 0);
}

// ============================ prep: m -> bf16 RM + TR ============================
// (round-4 version, verified) smf chunk-XOR swizzled: logical (row,d) at float
// index row*260 + ((d>>2)^(row>>3))*4 + (d&3); transpose gather conflict-free,
// mtr writes 128B-contiguous per 8 lanes.
__global__ __launch_bounds__(256)
void prep_m(const float* __restrict__ mg, ushort* __restrict__ mrm,
            ushort* __restrict__ mtr)
{
  __shared__ float smf[64 * 260];
  const int tid = threadIdx.x;
  const int b   = blockIdx.x & 15;
  const int kt  = blockIdx.x >> 4;      // 0..27, 64-key chunks
  const int k0  = kt * 64;
  const float* mb = mg + (size_t)b * NQ * DIM;

  #pragma unroll
  for (int i = 0; i < 16; ++i) {
    const int idx = i * 256 + tid;
    const int row = idx >> 6;           // 0..63 (key within chunk)
    const int ch  = idx & 63;           // 4-float chunk of d
    const int c4  = ch * 4;
    const int gk  = k0 + row;
    float4v v = (gk < NQ) ? *(const float4v*)(mb + (size_t)gk * DIM + c4)
                          : (float4v){0.f, 0.f, 0.f, 0.f};
    *(float4v*)&smf[row * 260 + ((ch ^ (row >> 3)) << 2)] = v;
    union { short4v v4; short e[4]; } h;
    #pragma unroll
    for (int j = 0; j < 4; ++j) h.e[j] = (short)f2bf(v[j]);
    *(short4v*)(mrm + ((size_t)b * NQP + k0 + row) * DIM + c4) = h.v4;
  }
  __syncthreads();

  const int wv = tid >> 6;        // wave 0..3
  const int ln = tid & 63;
  const int dr = ln >> 3;         // 0..7: d-row within the 8-row strip
  const int kc = ln & 7;          // 0..7: 16B key-chunk within the 64-key block
  #pragma unroll
  for (int it = 0; it < 8; ++it) {
    const int d  = wv * 64 + it * 8 + dr;
    const int dc = d >> 2;        // logical 4-float chunk of d
    const int de = d & 3;
    union { short8v v; short e[8]; } u;
    #pragma unroll
    for (int j = 0; j < 8; ++j)
      u.e[j] = (short)f2bf(smf[(kc * 8 + j) * 260 + ((dc ^ kc) << 2) + de]);
    *(short8v*)(mtr + ((size_t)b * DIM + d) * NQP + k0 + kc * 8) = u.v;
  }
}

// ============================ attention ============================
// PRODUCER-CONSUMER WAVE SPECIALIZATION: 448 blocks x 4 waves, 2 blocks/CU.
// Waves 0,1 = QK waves (pair pp = w): QK[t] + exp + P-write for 32 queries.
// Waves 2,3 = PV waves (pair pp = w-2): P-read + PV[t-1] for the same 32 q.
// P and TR are tile-parity double-buffered, so ONE barrier/iter hands off
// P[t-1] and syncs staging. The exp -> P-roundtrip chain no longer gates any
// PV MFMA (round-6's barrier2 phase-locked all waves through it).
// Staging: RM[t+1] and TR[t] issued together right after the barrier -- same
// global-access locality as round 6 (FETCH tripwire: must stay ~43MB).
// All reads/swizzles identical to round 5/6 (proven).

static __device__ __forceinline__ void stage_RM(const ushort* mrb, ushort* smb,
                                                int k0, int w, int lane)
{
  // RM [k][cs] <- global d-chunk cs^(k&7)  (swizzle in the global address)
  #pragma unroll
  for (int j = 0; j < 4; ++j) {
    const int L  = (w * 4 + j) * 64 + lane;   // 0..1023
    const int k  = L >> 5;
    const int cs = L & 31;
    const int gc = cs ^ (k & 7);
    dma16(mrb + (size_t)(k0 + k) * DIM + gc * 8, smb + (w * 4 + j) * 512);
  }
}

static __device__ __forceinline__ void stage_TR(const ushort* mtb, ushort* smb,
                                                int k0, int w, int lane)
{
  // TR [d][t] <- global key-chunk t ^ (d&3) ^ ((d>>2)&3)
  #pragma unroll
  for (int j = 0; j < 4; ++j) {
    const int L = (w * 4 + j) * 64 + lane;
    const int d = L >> 2;
    const int t = L & 3;
    const int kc = (t ^ (d & 3) ^ ((d >> 2) & 3)) & 3;
    dma16(mtb + (size_t)d * NQP + k0 + kc * 8, smb + (w * 4 + j) * 512);
  }
}

__global__ __launch_bounds__(256, 2)
void attn_fused(const float* __restrict__ x, const ushort* __restrict__ mrm,
                const ushort* __restrict__ mtr, const int* __restrict__ maskg,
                const float* __restrict__ scale, float* __restrict__ out)
{
  __shared__ ushort sm[SM_TOTAL];
  const int tid  = threadIdx.x;
  const int w    = tid >> 6;      // 0..3
  const int lane = tid & 63;
  const int l15  = lane & 15;
  const int quad = lane >> 4;
  const int l7   = l15 & 7;
  const int role = w >> 1;        // 0 = QK producer, 1 = PV consumer
  const int pp   = w & 1;         // query pair (32 q each)

  const int b      = blockIdx.x & 15;
  const int qblk   = blockIdx.x >> 4;     // 0..27
  const int qbase0 = qblk * QBLK;
  const int qbase  = qbase0 + pp * 32;

  const float*  xb  = x + (size_t)b * NQ * DIM;
  const ushort* mrb = mrm + (size_t)b * NQP * DIM;
  const ushort* mtb = mtr + (size_t)b * DIM * NQP;
  const int*    mkb = maskg + (size_t)b * NQ;
  float*        ob  = out + (size_t)b * NQ * (2 * DIM);

  // ---- QK waves: resident Q fragments (two 16-q subtiles), Q = x*scale ----
  short8v qa0[8], qa1[8];
  if (role == 0) {
    int q0 = qbase + l15;      q0 = q0 < NQ ? q0 : NQ - 1;
    int q1 = qbase + 16 + l15; q1 = q1 < NQ ? q1 : NQ - 1;
    const float* xr0 = xb + (size_t)q0 * DIM;
    const float* xr1 = xb + (size_t)q1 * DIM;
    #pragma unroll
    for (int kk = 0; kk < 8; ++kk) {
      const int dof = kk * 32 + quad * 8;
      const float4v sa = *(const float4v*)(scale + dof);
      const float4v sb = *(const float4v*)(scale + dof + 4);
      const float4v a0 = *(const float4v*)(xr0 + dof);
      const float4v a1 = *(const float4v*)(xr0 + dof + 4);
      const float4v b0 = *(const float4v*)(xr1 + dof);
      const float4v b1 = *(const float4v*)(xr1 + dof + 4);
      union { short8v v; short e[8]; } u0, u1;
      #pragma unroll
      for (int j = 0; j < 4; ++j) {
        u0.e[j]     = (short)f2bf(a0[j] * sa[j]);
        u0.e[j + 4] = (short)f2bf(a1[j] * sb[j]);
        u1.e[j]     = (short)f2bf(b0[j] * sa[j]);
        u1.e[j + 4] = (short)f2bf(b1[j] * sb[j]);
      }
      qa0[kk] = u0.v;
      qa1[kk] = u1.v;
    }
  }

  // ---- PV waves: output accumulators ----
  float4v o0[16], o1[16];
  #pragma unroll
  for (int dt = 0; dt < 16; ++dt) {
    o0[dt] = (float4v){0.f, 0.f, 0.f, 0.f};
    o1[dt] = (float4v){0.f, 0.f, 0.f, 0.f};
  }
  float l0[4] = {0.f, 0.f, 0.f, 0.f};
  float l1[4] = {0.f, 0.f, 0.f, 0.f};

  // prologue: all waves stage RM[0]; QK waves load tile-0 masks
  stage_RM(mrb, sm, 0, w, lane);
  int mvc[2] = {0, 0};
  if (role == 0) {
    #pragma unroll
    for (int ks = 0; ks < 2; ++ks) {
      const int key = ks * 16 + l15;
      mvc[ks] = (key < NQ) ? mkb[key] : 0;
    }
  }

  #pragma unroll 1
  for (int t = 0; t <= NT; ++t) {
    __syncthreads();   // drains this wave's DMA; publishes P[t-1], TR[t-1], RM[t]

    if (t < NT)
      stage_TR(mtb, sm + TR_OFF + (t & 1) * TR_SZ, t * KT, w, lane);
    if (t + 1 < NT)
      stage_RM(mrb, sm + ((t + 1) & 1) * RM_SZ, (t + 1) * KT, w, lane);

    if (role == 0) {
      // ---- producer: QK[t] -> exp -> P[pp][t&1] ----
      int mvn[2] = {0, 0};
      if (t + 1 < NT) {
        #pragma unroll
        for (int ks = 0; ks < 2; ++ks) {
          const int key = (t + 1) * KT + ks * 16 + l15;
          mvn[ks] = (key < NQ) ? mkb[key] : 0;
        }
      }
      if (t < NT) {
        const ushort* rmp = sm + (t & 1) * RM_SZ;
        ushort* pb = sm + P_OFF + (pp * 2 + (t & 1)) * (32 * P_STRIDE);
        #pragma unroll
        for (int ks = 0; ks < 2; ++ks) {
          float4v s0 = (float4v){0.f, 0.f, 0.f, 0.f};
          float4v s1 = (float4v){0.f, 0.f, 0.f, 0.f};
          const ushort* rowp = rmp + (ks * 16 + l15) * DIM;
          #pragma unroll
          for (int kk = 0; kk < 8; ++kk) {
            const short8v bv = *(const short8v*)(rowp + (((kk * 4 + quad) ^ l7) * 8));
            s0 = __builtin_amdgcn_mfma_f32_16x16x32_bf16(qa0[kk], bv, s0, 0, 0, 0);
            s1 = __builtin_amdgcn_mfma_f32_16x16x32_bf16(qa1[kk], bv, s1, 0, 0, 0);
          }
          // P write: logical chunk (ks*2 + l15>>3) stored at chunk ^ quad
          const int pwc = (((ks * 2 + (l15 >> 3)) ^ quad) << 3) + l7;
          #pragma unroll
          for (int r = 0; r < 4; ++r) {
            const float p0 = mvc[ks] ? exp2f(s0[r] * 1.44269504089f) : 0.0f;
            const float p1 = mvc[ks] ? exp2f(s1[r] * 1.44269504089f) : 0.0f;
            l0[r] += p0;
            l1[r] += p1;
            pb[(quad * 4 + r) * P_STRIDE + pwc] = f2bf(p0);
            pb[(16 + quad * 4 + r) * P_STRIDE + pwc] = f2bf(p1);
          }
        }
        mvc[0] = mvn[0];
        mvc[1] = mvn[1];
      }
    } else {
      // ---- consumer: PV[t-1] from P[pp][(t-1)&1] and TR[(t-1)&1] ----
      if (t >= 1) {
        const ushort* trp = sm + TR_OFF + ((t - 1) & 1) * TR_SZ;
        const ushort* pb = sm + P_OFF + (pp * 2 + ((t - 1) & 1)) * (32 * P_STRIDE);
        // reader row>>2 & 3 == l15>>2, writer's == quad: physical = logical^swz
        const int pswz = ((quad ^ (l15 >> 2)) & 3) << 3;
        const short8v pa0 = *(const short8v*)(pb + l15 * P_STRIDE + pswz);
        const short8v pa1 = *(const short8v*)(pb + (16 + l15) * P_STRIDE + pswz);
        #pragma unroll
        for (int dt = 0; dt < 16; ++dt) {
          const int d = dt * 16 + l15;
          const short8v bv = *(const short8v*)(
              trp + d * KT + (((quad ^ (d & 3) ^ ((d >> 2) & 3)) & 3) * 8));
          o0[dt] = __builtin_amdgcn_mfma_f32_16x16x32_bf16(pa0, bv, o0[dt], 0, 0, 0);
          o1[dt] = __builtin_amdgcn_mfma_f32_16x16x32_bf16(pa1, bv, o1[dt], 0, 0, 0);
        }
      }
    }
  }

  // ---- QK waves: reduce l over the 16 lanes of each quad, publish to Lf ----
  float* Lf = (float*)(sm + L_OFF_HW);
  if (role == 0) {
    #pragma unroll
    for (int r = 0; r < 4; ++r) {
      float a = l0[r], c = l1[r];
      a += __shfl_xor(a, 1); a += __shfl_xor(a, 2);
      a += __shfl_xor(a, 4); a += __shfl_xor(a, 8);
      c += __shfl_xor(c, 1); c += __shfl_xor(c, 2);
      c += __shfl_xor(c, 4); c += __shfl_xor(c, 8);
      if (l15 == 0) {
        Lf[(pp * 2 + 0) * 16 + quad * 4 + r] = a;
        Lf[(pp * 2 + 1) * 16 + quad * 4 + r] = c;
      }
    }
  }
  __syncthreads();

  if (role == 1) {
    // ---- PV waves: normalize + transpose through LDS + coalesced stores ----
    float il0[4], il1[4];
    #pragma unroll
    for (int r = 0; r < 4; ++r) {
      il0[r] = 1.0f / Lf[(pp * 2 + 0) * 16 + quad * 4 + r];
      il1[r] = 1.0f / Lf[(pp * 2 + 1) * 16 + quad * 4 + r];
    }
    float* ew = (float*)sm + pp * 8320;   // [32 q][260] fp32, wave-private
    #pragma unroll
    for (int dt = 0; dt < 16; ++dt)
      #pragma unroll
      for (int r = 0; r < 4; ++r) {
        ew[(quad * 4 + r) * 260 + dt * 16 + l15]      = o0[dt][r] * il0[r];
        ew[(16 + quad * 4 + r) * 260 + dt * 16 + l15] = o1[dt][r] * il1[r];
      }
    #pragma unroll
    for (int i = 0; i < 8; ++i)
      #pragma unroll
      for (int jj = 0; jj < 4; ++jj) {
        const int row = i * 4 + quad;        // 0..31
        const int q   = qbase0 + pp * 32 + row;
        if (q < NQ) {
          const float4v v = *(const float4v*)&ew[row * 260 + (jj * 16 + l15) * 4];
          *(float4v*)(ob + (size_t)q * (2 * DIM) + DIM + (jj * 16 + l15) * 4) = v;
        }
      }
  } else {
    // ---- QK waves: copy x into first half of concat (block's 64 queries) ----
    #pragma unroll
    for (int i = 0; i < 32; ++i) {
      const int idx = i * 128 + pp * 64 + lane;   // 0..4095
      const int row = idx >> 6;                   // 0..63
      const int c4  = (idx & 63) * 4;
      const int q   = qbase0 + row;
      if (q < NQ) {
        const float4v v = *(const float4v*)(xb + (size_t)q * DIM + c4);
        *(float4v*)(ob + (size_t)q * (2 * DIM) + c4) = v;
      }
    }
  }
}

extern "C" void kernel_launch(void* const* d_in, const int* in_sizes, int n_in,
                              void* d_out, int out_size, void* d_ws, size_t ws_size,
                              hipStream_t stream) {
  const float* x     = (const float*)d_in[0];
  const float* mem   = (const float*)d_in[1];
  const int*   mask  = (const int*)d_in[2];
  // d_in[3] = w_lin: cancels in softmax (per-row constant) — unused
  const float* scale = (const float*)d_in[4];
  float* out = (float*)d_out;

  ushort* wsm = (ushort*)d_ws;               // bf16 m, row-major [16][1792][256]
  ushort* wst = wsm + WS_MRM_SZ;             // bf16 m, transposed [16][256][1792]

  prep_m<<<dim3(448), dim3(256), 0, stream>>>(mem, wsm, wst);
  // 16 batches x 28 q-blocks of 64 queries = 448 blocks, 2 blocks/CU:
  // producer-consumer wave pairs (QK waves 0-1, PV waves 2-3), 1 barrier/iter
  attn_fused<<<dim3(448), dim3(256), 0, stream>>>(x, wsm, wst, mask, scale, out);
}